// Round 9
// baseline (1596.979 us; speedup 1.0000x reference)
//
#include <hip/hip_runtime.h>
#include <hip/hip_bf16.h>
#include <cstdint>
#include <cstddef>

// Problem constants
#define H_    1024
#define DI_   2048
#define DS_   16
#define DTR_  64
#define NL_   4
#define LLM_  4096
#define B_    4
#define L_    1024
#define MEMID 50279
#define KTOK  16
#define MROWS (B_*L_)   // 4096
#define BK    64

using bf16 = __hip_bfloat16;
typedef __attribute__((ext_vector_type(8))) short short8;
typedef __attribute__((ext_vector_type(4))) short short4v;
typedef __attribute__((ext_vector_type(4))) float floatx4;
typedef __attribute__((ext_vector_type(4))) unsigned int uint4v;

__device__ __forceinline__ float b2f(bf16 v){ return __bfloat162float(v); }
__device__ __forceinline__ bf16  f2b(float v){ return __float2bfloat16(v); }
__device__ __forceinline__ float sh2f(short s){
    unsigned u = ((unsigned)(unsigned short)s) << 16;
    return __builtin_bit_cast(float, u);
}
__device__ __forceinline__ short f2sh(float v){
    bf16 b = f2b(v);
    return __builtin_bit_cast(short, b);
}
__device__ __forceinline__ float bcf(unsigned int u){ return __builtin_bit_cast(float, u); }

// fused-DPP 16-lane row sum; result valid in lane 15 of each 16-lane row
__device__ __forceinline__ float rowsum16(float v){
    float t;
    asm("v_add_f32_dpp %0, %1, %1 row_shr:1 row_mask:0xf bank_mask:0xf bound_ctrl:0" : "=v"(t) : "v"(v));
    asm("v_add_f32_dpp %0, %1, %1 row_shr:2 row_mask:0xf bank_mask:0xf bound_ctrl:0" : "=v"(v) : "v"(t));
    asm("v_add_f32_dpp %0, %1, %1 row_shr:4 row_mask:0xf bank_mask:0xf bound_ctrl:0" : "=v"(t) : "v"(v));
    asm("v_add_f32_dpp %0, %1, %1 row_shr:8 row_mask:0xf bank_mask:0xf bound_ctrl:0" : "=v"(v) : "v"(t));
    return v;
}

// async global->LDS, 16B per lane; LDS dest = wave-uniform base + lane*16
__device__ __forceinline__ void async16(bf16* l, const bf16* g){
    __builtin_amdgcn_global_load_lds(
        (const __attribute__((address_space(1))) void*)g,
        (__attribute__((address_space(3))) void*)l,
        16, 0, 0);
}

// ---------------- fused prep: cvt4 (per-layer weights) + rmsnorm (+ embed when ids!=null)
// blocks [0, MROWS): (embed row if ids) + rmsnorm row -> xn
// blocks [MROWS, MROWS+6464): 4-segment f32->bf16 weight convert
__global__ void prep_kernel(const int* __restrict__ ids,
                            const float* __restrict__ emb,
                            float* __restrict__ h,
                            const float* __restrict__ nw,
                            bf16* __restrict__ xn,
                            const float* __restrict__ s0, bf16* __restrict__ d0, int t0,
                            const float* __restrict__ s1, bf16* __restrict__ d1, int t1,
                            const float* __restrict__ s2, bf16* __restrict__ d2, int t2,
                            const float* __restrict__ s3, bf16* __restrict__ d3, int t3)
{
    int bid = blockIdx.x;
    if (bid < MROWS){
        float4 v;
        if (ids){
            int id = ids[bid];
            v = ((const float4*)(emb + (size_t)id * H_))[threadIdx.x];
            ((float4*)(h + (size_t)bid * H_))[threadIdx.x] = v;
        } else {
            v = ((const float4*)(h + (size_t)bid * H_))[threadIdx.x];
        }
        float ss = v.x*v.x + v.y*v.y + v.z*v.z + v.w*v.w;
        #pragma unroll
        for (int off = 32; off; off >>= 1) ss += __shfl_down(ss, off, 64);
        __shared__ float red[4];
        __shared__ float scale_s;
        int lane = threadIdx.x & 63, wv = threadIdx.x >> 6;
        if (lane == 0) red[wv] = ss;
        __syncthreads();
        if (threadIdx.x == 0){
            float t = red[0]+red[1]+red[2]+red[3];
            scale_s = rsqrtf(t * (1.f/H_) + 1e-5f);
        }
        __syncthreads();
        float sc = scale_s;
        float4 w4 = ((const float4*)nw)[threadIdx.x];
        short4v o;
        o[0] = f2sh(v.x * sc * w4.x);
        o[1] = f2sh(v.y * sc * w4.y);
        o[2] = f2sh(v.z * sc * w4.z);
        o[3] = f2sh(v.w * sc * w4.w);
        ((short4v*)(xn + (size_t)bid*H_))[threadIdx.x] = o;
    } else {
        int i = (bid - MROWS)*256 + threadIdx.x;      // float4 index
        const float* s; bf16* d; int local;
        if      (i < t0){ s=s0; d=d0; local=i; }
        else if (i < t1){ s=s1; d=d1; local=i-t0; }
        else if (i < t2){ s=s2; d=d2; local=i-t1; }
        else if (i < t3){ s=s3; d=d3; local=i-t2; }
        else return;
        float4 f = ((const float4*)s)[local];
        short4v o; o[0]=f2sh(f.x); o[1]=f2sh(f.y); o[2]=f2sh(f.z); o[3]=f2sh(f.w);
        ((short4v*)d)[local] = o;
    }
}

// ---------------- MFMA GEMM, LDS-staged, BK=64, XOR-swizzled LDS (T2):
// staging pre-permutes the GLOBAL source column-block so linear global_load_lds
// dests receive swizzled content; ds_read XORs the block index with (row&7).
// C[m,n] = sum_k A[m,k]*B[n,k]
// mode 1: Cb[n*ldc+m] = bf16(softplus(acc+bias[n]))   TRANSPOSED (dt_t)
// mode 3: Cb[m*ldc+n] = bf16(acc)                (row-major)
__launch_bounds__(256)
__global__ void gemm_bt(const bf16* __restrict__ A, int lda,
                        const bf16* __restrict__ Bm, int ldb,
                        int M, int N, int K,
                        float* __restrict__ Cf, bf16* __restrict__ Cb, int ldc,
                        const float* __restrict__ bias, int mode)
{
    __shared__ __align__(16) bf16 sA[128*BK];   // 16 KB
    __shared__ __align__(16) bf16 sB[128*BK];   // 16 KB

    int tid  = threadIdx.x;
    int lane = tid & 63;
    int wv   = tid >> 6;          // 4 waves, 2x2 of 64x64
    int quad = lane >> 4, r16 = lane & 15;
    int m0 = blockIdx.y*128, n0 = blockIdx.x*128;
    int wm = (wv>>1)*64, wn = (wv&1)*64;

    int rr = tid >> 3;                         // 0..31
    int kc = ((tid & 7) ^ (rr & 7)) * 8;       // swizzled source col-block
    const bf16* pA = A  + (size_t)(m0 + rr)*lda + kc;
    const bf16* pB = Bm + (size_t)(n0 + rr)*ldb + kc;
    bf16* lA = sA + wv*512;
    bf16* lB = sB + wv*512;

    floatx4 acc[4][4];
    #pragma unroll
    for (int i=0;i<4;i++)
        #pragma unroll
        for (int j=0;j<4;j++) acc[i][j] = (floatx4){0.f,0.f,0.f,0.f};

    for (int k0 = 0; k0 < K; k0 += BK){
        async16(lA,        pA);
        async16(lA + 2048, pA + (size_t)32*lda);
        async16(lA + 4096, pA + (size_t)64*lda);
        async16(lA + 6144, pA + (size_t)96*lda);
        async16(lB,        pB);
        async16(lB + 2048, pB + (size_t)32*ldb);
        async16(lB + 4096, pB + (size_t)64*ldb);
        async16(lB + 6144, pB + (size_t)96*ldb);
        pA += BK; pB += BK;
        __syncthreads();

        #pragma unroll
        for (int kk=0; kk<2; kk++){
            short8 a[4], b[4];
            #pragma unroll
            for (int i=0;i<4;i++)
                a[i] = *(const short8*)(sA + (wm + i*16 + r16)*BK
                                          + (((kk*4+quad) ^ (r16 & 7))*8));
            #pragma unroll
            for (int j=0;j<4;j++)
                b[j] = *(const short8*)(sB + (wn + j*16 + r16)*BK
                                          + (((kk*4+quad) ^ (r16 & 7))*8));
            #pragma unroll
            for (int i=0;i<4;i++)
                #pragma unroll
                for (int j=0;j<4;j++)
                    acc[i][j] = __builtin_amdgcn_mfma_f32_16x16x32_bf16(a[i], b[j], acc[i][j], 0, 0, 0);
        }
        __syncthreads();
    }

    #pragma unroll
    for (int i=0;i<4;i++)
        #pragma unroll
        for (int j=0;j<4;j++){
            int mq = m0 + wm + i*16 + quad*4;
            int n  = n0 + wn + j*16 + r16;
            if (mode == 1){
                if (n < N){
                    short4v pk;
                    #pragma unroll
                    for (int rr2=0;rr2<4;rr2++){
                        float xx = acc[i][j][rr2] + bias[n];
                        float sp = (xx > 20.f) ? xx : log1pf(__expf(xx));
                        pk[rr2] = f2sh(sp);
                    }
                    *(short4v*)(Cb + (size_t)n*ldc + mq) = pk;
                }
            } else {
                #pragma unroll
                for (int rr2=0;rr2<4;rr2++){
                    int m = mq + rr2;
                    if (m < M && n < N)
                        Cb[(size_t)m*ldc + n] = f2b(acc[i][j][rr2]);
                }
            }
        }
}

// ---------------- out-proj / head GEMM: BM=128, BN=64, XOR-swizzled LDS.
// mode 2: Cf[m*ldc+n] += acc (unguarded, M multiple of 128)
// mode 0: if (m<M) Cf[m*ldc+n] = acc + bias[n]
__launch_bounds__(256)
__global__ void gemm_out(const bf16* __restrict__ A, int lda,
                         const bf16* __restrict__ Bm, int ldb,
                         int K, int M,
                         float* __restrict__ Cf, int ldc,
                         const float* __restrict__ bias, int mode)
{
    __shared__ __align__(16) bf16 sA[128*BK];   // 16 KB
    __shared__ __align__(16) bf16 sB[64*BK];    //  8 KB

    int tid  = threadIdx.x;
    int lane = tid & 63;
    int wv   = tid >> 6;           // 4 waves, 2x2 of 64x32
    int quad = lane >> 4, r16 = lane & 15;
    int m0 = blockIdx.y*128, n0 = blockIdx.x*64;
    int wm = (wv>>1)*64, wn = (wv&1)*32;

    int rr = tid >> 3;                         // 0..31
    int kc = ((tid & 7) ^ (rr & 7)) * 8;       // swizzled source col-block
    const bf16* pA = A  + (size_t)(m0 + rr)*lda + kc;
    const bf16* pB = Bm + (size_t)(n0 + rr)*ldb + kc;
    bf16* lA = sA + wv*512;
    bf16* lB = sB + wv*512;

    floatx4 acc[4][2];
    #pragma unroll
    for (int i=0;i<4;i++)
        #pragma unroll
        for (int j=0;j<2;j++) acc[i][j] = (floatx4){0.f,0.f,0.f,0.f};

    for (int k0 = 0; k0 < K; k0 += BK){
        async16(lA,        pA);
        async16(lA + 2048, pA + (size_t)32*lda);
        async16(lA + 4096, pA + (size_t)64*lda);
        async16(lA + 6144, pA + (size_t)96*lda);
        async16(lB,        pB);
        async16(lB + 2048, pB + (size_t)32*ldb);
        pA += BK; pB += BK;
        __syncthreads();

        #pragma unroll
        for (int kk=0; kk<2; kk++){
            short8 a[4], b[2];
            #pragma unroll
            for (int i=0;i<4;i++)
                a[i] = *(const short8*)(sA + (wm + i*16 + r16)*BK
                                          + (((kk*4+quad) ^ (r16 & 7))*8));
            #pragma unroll
            for (int j=0;j<2;j++)
                b[j] = *(const short8*)(sB + (wn + j*16 + r16)*BK
                                          + (((kk*4+quad) ^ (r16 & 7))*8));
            #pragma unroll
            for (int i=0;i<4;i++)
                #pragma unroll
                for (int j=0;j<2;j++)
                    acc[i][j] = __builtin_amdgcn_mfma_f32_16x16x32_bf16(a[i], b[j], acc[i][j], 0, 0, 0);
        }
        __syncthreads();
    }

    #pragma unroll
    for (int i=0;i<4;i++)
        #pragma unroll
        for (int j=0;j<2;j++){
            int mq = m0 + wm + i*16 + quad*4;
            int n  = n0 + wn + j*16 + r16;
            if (mode == 2){
                #pragma unroll
                for (int rr2=0;rr2<4;rr2++)
                    Cf[(size_t)(mq+rr2)*ldc + n] += acc[i][j][rr2];
            } else {
                #pragma unroll
                for (int rr2=0;rr2<4;rr2++){
                    int m = mq + rr2;
                    if (m < M)
                        Cf[(size_t)m*ldc + n] = acc[i][j][rr2] + bias[n];
                }
            }
        }
}

// ---------------- specialized ssm GEMM: M=4096, N=96, K=2048, BM=32
// grid (128, 2): blockIdx.y=0 -> cols 0..63 (dtA), blockIdx.y=1 -> cols 64..95 (B/C).
// FULLY STATIC per-branch code (rule #20: no runtime-bounded loops over
// accumulator arrays — round-7 version spilled acc[] to scratch).
__launch_bounds__(256)
__global__ void gemm_ssm(const bf16* __restrict__ A,    // u, lda = DI_
                         const bf16* __restrict__ Bm,   // wb_xw, ldb = DI_
                         bf16* __restrict__ dtA,
                         bf16* __restrict__ pBt,
                         bf16* __restrict__ pCt)
{
    __shared__ __align__(16) bf16 sA2[32*64];   // 4 KB
    __shared__ __align__(16) bf16 sB2[64*64];   // 8 KB

    int tid  = threadIdx.x;
    int lane = tid & 63;
    int wv   = tid >> 6;           // 4 waves: 2x2
    int quad = lane >> 4, r16 = lane & 15;
    int m0 = blockIdx.x * 32;
    int wr = wv >> 1, wc = wv & 1;

    int ar = tid >> 3;                          // 0..31
    int kc = ((tid & 7) ^ (ar & 7)) * 8;        // swizzled source col-block
    const bf16* pA  = A  + (size_t)(m0 + ar)*DI_ + kc;
    bf16* lA  = sA2 + wv*512;

    if (blockIdx.y == 0){
        // cols 0..63 -> dtA; each wave does 2 static n-frags at wc*32 + {0,16}
        const bf16* pB0 = Bm + (size_t)(ar)     *DI_ + kc;
        const bf16* pB1 = Bm + (size_t)(32 + ar)*DI_ + kc;
        bf16* lB0 = sB2 + wv*512;
        bf16* lB1 = sB2 + 2048 + wv*512;
        floatx4 acc0 = (floatx4){0.f,0.f,0.f,0.f};
        floatx4 acc1 = (floatx4){0.f,0.f,0.f,0.f};
        for (int k0 = 0; k0 < DI_; k0 += 64){
            async16(lA,  pA);
            async16(lB0, pB0);
            async16(lB1, pB1);
            pA += 64; pB0 += 64; pB1 += 64;
            __syncthreads();
            #pragma unroll
            for (int kk=0; kk<2; kk++){
                int swz = ((kk*4+quad) ^ (r16 & 7))*8;
                short8 a  = *(const short8*)(sA2 + (wr*16 + r16)*64 + swz);
                short8 b0 = *(const short8*)(sB2 + (wc*32 + r16)*64 + swz);
                short8 b1 = *(const short8*)(sB2 + (wc*32 + 16 + r16)*64 + swz);
                acc0 = __builtin_amdgcn_mfma_f32_16x16x32_bf16(a, b0, acc0, 0, 0, 0);
                acc1 = __builtin_amdgcn_mfma_f32_16x16x32_bf16(a, b1, acc1, 0, 0, 0);
            }
            __syncthreads();
        }
        int mq = m0 + wr*16 + quad*4;
        int na = wc*32 + r16;
        int nb = wc*32 + 16 + r16;
        #pragma unroll
        for (int rr2=0;rr2<4;rr2++){
            dtA[(size_t)(mq+rr2)*64 + na] = f2b(acc0[rr2]);
            dtA[(size_t)(mq+rr2)*64 + nb] = f2b(acc1[rr2]);
        }
    } else {
        // cols 64..95 -> pBt (wc=0) / pCt (wc=1); 1 static n-frag per wave
        const bf16* pBs = Bm + (size_t)(64 + ar)*DI_ + kc;
        bf16* lB0 = sB2 + wv*512;
        floatx4 acc0 = (floatx4){0.f,0.f,0.f,0.f};
        for (int k0 = 0; k0 < DI_; k0 += 64){
            async16(lA,  pA);
            async16(lB0, pBs);
            pA += 64; pBs += 64;
            __syncthreads();
            #pragma unroll
            for (int kk=0; kk<2; kk++){
                int swz = ((kk*4+quad) ^ (r16 & 7))*8;
                short8 a  = *(const short8*)(sA2 + (wr*16 + r16)*64 + swz);
                short8 b0 = *(const short8*)(sB2 + (wc*16 + r16)*64 + swz);
                acc0 = __builtin_amdgcn_mfma_f32_16x16x32_bf16(a, b0, acc0, 0, 0, 0);
            }
            __syncthreads();
        }
        int mq = m0 + wr*16 + quad*4;
        short4v pk;
        #pragma unroll
        for (int rr2=0;rr2<4;rr2++) pk[rr2] = f2sh(acc0[rr2]);
        if (wc == 0) *(short4v*)(pBt + (size_t)r16*MROWS + mq) = pk;
        else         *(short4v*)(pCt + (size_t)r16*MROWS + mq) = pk;
    }
}

// ---------------- causal depthwise conv (k=4) + silu, vectorized short8;
// writes u (row-major) and u_t ([d][bt])
__global__ void conv_silu_kernel(const bf16* __restrict__ xz,
                                 const float* __restrict__ cw,
                                 const float* __restrict__ cb,
                                 bf16* __restrict__ u,
                                 bf16* __restrict__ u_t)
{
    __shared__ float tile[64][65];
    int bt0 = blockIdx.x * 64;
    int d0  = blockIdx.y * 64;
    int tid = threadIdx.x;
    const short8 z8 = {0,0,0,0,0,0,0,0};
    #pragma unroll
    for (int it = 0; it < 2; it++){
        int task = it*256 + tid;        // 0..511
        int g    = task & 7;            // d-group (8 channels)
        int tr   = task >> 3;           // 0..63
        int row  = bt0 + tr;
        int t    = row & (L_-1);
        int d8   = d0 + g*8;
        const bf16* base = xz + (size_t)row*(2*DI_) + d8;
        short8 x3 = *(const short8*)(base);
        short8 x2 = (t>=1) ? *(const short8*)(base - 1*(2*DI_)) : z8;
        short8 x1 = (t>=2) ? *(const short8*)(base - 2*(2*DI_)) : z8;
        short8 x0 = (t>=3) ? *(const short8*)(base - 3*(2*DI_)) : z8;
        short8 out;
        #pragma unroll
        for (int j=0;j<8;j++){
            int d = d8 + j;
            float4 w4 = ((const float4*)cw)[d];
            float acc = cb[d];
            acc += sh2f(x0[j])*w4.x;
            acc += sh2f(x1[j])*w4.y;
            acc += sh2f(x2[j])*w4.z;
            acc += sh2f(x3[j])*w4.w;
            float s = acc / (1.f + __expf(-acc));
            out[j] = f2sh(s);
            tile[g*8+j][tr] = s;
        }
        *(short8*)(u + (size_t)row*DI_ + d8) = out;
    }
    __syncthreads();
    #pragma unroll
    for (int it = 0; it < 2; it++){
        int task = it*256 + tid;
        int g    = task & 7;            // t-group (8 timesteps)
        int dr   = task >> 3;           // 0..63
        int tc8  = g*8;
        short8 o;
        #pragma unroll
        for (int j=0;j<8;j++) o[j] = f2sh(tile[dr][tc8+j]);
        *(short8*)(u_t + (size_t)(d0+dr)*MROWS + bt0 + tc8) = o;
    }
}

// ---------------- selective scan, time-vectorized x8, fused-DPP reduce,
// depth-4 rotating register prefetch (statically indexed, unclamped —
// tail over-reads stay inside the workspace and are never consumed),
// dword bf16 decode, cvt_pk pack
#define SCAN_GROUP(dtv,uv,bv,cv,gidx) { \
    uint4v yo; \
    _Pragma("unroll") \
    for (int j = 0; j < 4; j++){ \
        unsigned int wdt = (dtv)[j], wu = (uv)[j], wB = (bv)[j], wC = (cv)[j]; \
        float dt0 = bcf(wdt << 16), u0 = bcf(wu << 16); \
        float b0  = bcf(wB  << 16), c0 = bcf(wC << 16); \
        float e0; asm("v_exp_f32 %0, %1" : "=v"(e0) : "v"(dt0 * A2)); \
        state = __builtin_fmaf(state, e0, dt0 * u0 * b0); \
        float y0 = __builtin_fmaf(u0, Dv, rowsum16(state * c0)); \
        float dt1 = bcf(wdt & 0xffff0000u), u1 = bcf(wu & 0xffff0000u); \
        float b1  = bcf(wB  & 0xffff0000u), c1 = bcf(wC & 0xffff0000u); \
        float e1; asm("v_exp_f32 %0, %1" : "=v"(e1) : "v"(dt1 * A2)); \
        state = __builtin_fmaf(state, e1, dt1 * u1 * b1); \
        float y1 = __builtin_fmaf(u1, Dv, rowsum16(state * c1)); \
        unsigned int pk; \
        asm("v_cvt_pk_bf16_f32 %0, %1, %2" : "=v"(pk) : "v"(y0), "v"(y1)); \
        yo[j] = pk; \
    } \
    if (s_idx == 15) yp_[gidx] = yo; \
}

__global__ void scan_kernel(const bf16* __restrict__ dt_t,
                            const bf16* __restrict__ u_t,
                            const bf16* __restrict__ sB_t,
                            const bf16* __restrict__ sC_t,
                            const float* __restrict__ A_log,
                            const float* __restrict__ Dp,
                            bf16* __restrict__ y_t)
{
    int lane  = threadIdx.x & 63;
    int wv    = threadIdx.x >> 6;
    int s_idx = lane & 15;
    int ch    = lane >> 4;
    int c = blockIdx.x*16 + wv*4 + ch;      // 0..8191 channel (b,d)
    int d = c & (DI_-1);
    int b = c >> 11;
    // pre-scale A by log2(e): per-step decay uses v_exp_f32 (2^x) directly
    float A2 = -__expf(A_log[d*DS_ + s_idx]) * 1.4426950408889634f;
    float Dv = Dp[d];
    const uint4v* dtp = (const uint4v*)(dt_t + (size_t)d*MROWS + b*L_);
    const uint4v* utp = (const uint4v*)(u_t  + (size_t)d*MROWS + b*L_);
    const uint4v* Bp  = (const uint4v*)(sB_t + (size_t)s_idx*MROWS + b*L_);
    const uint4v* Cp  = (const uint4v*)(sC_t + (size_t)s_idx*MROWS + b*L_);
    uint4v* yp_ = (uint4v*)(y_t + (size_t)d*MROWS + b*L_);

    const int NG = L_/8;   // 128 groups of 8 timesteps
    float state = 0.f;

    // depth-4 rotating prefetch (all indices static; NG % 4 == 0)
    uint4v dA = dtp[0], uA = utp[0], bA = Bp[0], cA = Cp[0];
    uint4v dB = dtp[1], uB = utp[1], bB = Bp[1], cB = Cp[1];
    uint4v dC = dtp[2], uC = utp[2], bC = Bp[2], cC = Cp[2];
    uint4v dD = dtp[3], uD = utp[3], bD = Bp[3], cD = Cp[3];

    for (int g = 0; g < NG; g += 4){
        SCAN_GROUP(dA, uA, bA, cA, g);
        dA = dtp[g+4]; uA = utp[g+4]; bA = Bp[g+4]; cA = Cp[g+4];
        SCAN_GROUP(dB, uB, bB, cB, g+1);
        dB = dtp[g+5]; uB = utp[g+5]; bB = Bp[g+5]; cB = Cp[g+5];
        SCAN_GROUP(dC, uC, bC, cC, g+2);
        dC = dtp[g+6]; uC = utp[g+6]; bC = Bp[g+6]; cC = Cp[g+6];
        SCAN_GROUP(dD, uD, bD, cD, g+3);
        dD = dtp[g+7]; uD = utp[g+7]; bD = Bp[g+7]; cD = Cp[g+7];
    }
}

// ---------------- gate + transpose, vectorized short8: xz[:, :DI] = y * silu(z)
__global__ void gate_kernel(const bf16* __restrict__ y_t,
                            bf16* __restrict__ xz)
{
    __shared__ float tile[64][65];
    int bt0 = blockIdx.x * 64;
    int d0  = blockIdx.y * 64;
    int tid = threadIdx.x;
    #pragma unroll
    for (int it = 0; it < 2; it++){
        int task = it*256 + tid;        // 0..511
        int g    = task & 7;            // bt-group (8 timesteps)
        int dr   = task >> 3;           // 0..63
        short8 v = *(const short8*)(y_t + (size_t)(d0+dr)*MROWS + bt0 + g*8);
        #pragma unroll
        for (int j=0;j<8;j++) tile[dr][g*8+j] = sh2f(v[j]);
    }
    __syncthreads();
    #pragma unroll
    for (int it = 0; it < 2; it++){
        int task = it*256 + tid;
        int g    = task & 7;            // d-group (8 channels)
        int tr   = task >> 3;           // 0..63
        int row  = bt0 + tr;
        int d8   = g*8;
        short8 z8 = *(const short8*)(xz + (size_t)row*(2*DI_) + DI_ + d0 + d8);
        short8 o;
        #pragma unroll
        for (int j=0;j<8;j++){
            float z  = sh2f(z8[j]);
            float sz = z / (1.f + __expf(-z));
            o[j] = f2sh(tile[d8+j][tr] * sz);
        }
        *(short8*)(xz + (size_t)row*(2*DI_) + d0 + d8) = o;
    }
}

// ---------------- tail: featnorm with inline pos recompute (blocks 0..63)
//                  + head projw f32->bf16 convert (blocks 64..)
__global__ void tail_kernel(const float* __restrict__ h,
                            const float* __restrict__ w,
                            const int* __restrict__ ids,
                            bf16* __restrict__ feats,
                            const float* __restrict__ projw,
                            bf16* __restrict__ wb, int n4)
{
    if (blockIdx.x < B_*KTOK){
        int bk = blockIdx.x;
        int b = bk >> 4, k = bk & 15;
        int t = threadIdx.x;
        __shared__ int cnt[256];
        __shared__ int pos_s;
        int local = 0;
        #pragma unroll
        for (int i=0;i<4;i++)
            if (ids[b*L_ + t*4 + i] == MEMID) local++;
        cnt[t] = local;
        __syncthreads();
        if (t == 0){
            int run = 0;
            for (int i=0;i<256;i++){ int tmp = cnt[i]; cnt[i] = run; run += tmp; }
        }
        __syncthreads();
        int rank = cnt[t];
        #pragma unroll
        for (int i=0;i<4;i++){
            int l = t*4 + i;
            if (ids[b*L_ + l] == MEMID){
                if (rank == k) pos_s = l;
                rank++;
            }
        }
        __syncthreads();
        int row = b*L_ + pos_s;
        float4 v = ((const float4*)(h + (size_t)row * H_))[t];
        float ss = v.x*v.x + v.y*v.y + v.z*v.z + v.w*v.w;
        #pragma unroll
        for (int off = 32; off; off >>= 1) ss += __shfl_down(ss, off, 64);
        __shared__ float red[4];
        __shared__ float scale_s;
        int lane = t & 63, wv = t >> 6;
        if (lane == 0) red[wv] = ss;
        __syncthreads();
        if (t == 0){
            float tt = red[0]+red[1]+red[2]+red[3];
            scale_s = rsqrtf(tt * (1.f/H_) + 1e-5f);
        }
        __syncthreads();
        float sc = scale_s;
        float4 w4 = ((const float4*)w)[t];
        short4v o;
        o[0] = f2sh(v.x * sc * w4.x);
        o[1] = f2sh(v.y * sc * w4.y);
        o[2] = f2sh(v.z * sc * w4.z);
        o[3] = f2sh(v.w * sc * w4.w);
        ((short4v*)(feats + (size_t)bk*H_))[t] = o;
    } else {
        int i = (blockIdx.x - B_*KTOK)*256 + threadIdx.x;
        if (i < n4){
            float4 f = ((const float4*)projw)[i];
            short4v o; o[0]=f2sh(f.x); o[1]=f2sh(f.y); o[2]=f2sh(f.z); o[3]=f2sh(f.w);
            ((short4v*)wb)[i] = o;
        }
    }
}

extern "C" void kernel_launch(void* const* d_in, const int* in_sizes, int n_in,
                              void* d_out, int out_size, void* d_ws, size_t ws_size,
                              hipStream_t stream)
{
    const int*   ids    = (const int*)  d_in[0];
    const float* emb    = (const float*)d_in[1];
    const float* norm_w = (const float*)d_in[2];
    const float* in_w   = (const float*)d_in[3];
    const float* cw     = (const float*)d_in[4];
    const float* cb     = (const float*)d_in[5];
    const float* xw     = (const float*)d_in[6];
    const float* dtw    = (const float*)d_in[7];
    const float* dtb    = (const float*)d_in[8];
    const float* A_log  = (const float*)d_in[9];
    const float* Dp     = (const float*)d_in[10];
    const float* ow     = (const float*)d_in[11];
    const float* fnw    = (const float*)d_in[12];
    const float* projw  = (const float*)d_in[13];
    const float* projb  = (const float*)d_in[14];
    float* out          = (float*)d_out;

    // workspace layout (bytes); total = 106,430,720 (known-good)
    char* ws = (char*)d_ws;
    float* h     = (float*)(ws + 0);             // 16.78 MB
    bf16*  xn    = (bf16*) (ws + 16777216);      //  8.39 MB
    bf16*  wb_in = (bf16*) (ws + 25165824);      //  8.39 MB (also: head proj bf16)
    bf16*  u     = (bf16*) (ws + 16777216);      // 16.78 MB overlay (xn+wb_in)
    bf16*  dt_t  = (bf16*) (ws + 16777216);      // 16.78 MB overlay (same)
    bf16*  xz    = (bf16*) (ws + 33554432);      // 33.55 MB
    bf16*  u_t   = (bf16*) (ws + 67108864);      // 16.78 MB
    bf16*  y_t   = (bf16*) (ws + 83886080);      // 16.78 MB
    bf16*  dtA   = (bf16*) (ws + 100663296);     //  0.52 MB (4096x64)
    bf16*  sB_t  = (bf16*) (ws + 101187584);     //  0.13 MB (16x4096)
    bf16*  sC_t  = (bf16*) (ws + 101318656);     //  0.13 MB
    bf16*  fe    = (bf16*) (ws + 101449728);     //  0.13 MB
    int*   pos   = (int*)  (ws + 101580800);     //  256 B (unused now)
    bf16*  wb_ow = (bf16*) (ws + 101581056);     //  4.19 MB
    bf16*  wb_xw = (bf16*) (ws + 105775360);     //  0.39 MB
    bf16*  wb_dtw= (bf16*) (ws + 106168576);     //  0.26 MB -> end 106430720
    (void)pos;

    const int n_in_w  = 2*DI_*H_;     // 4,194,304
    const int n_ow_w  = H_*DI_;       // 2,097,152
    const int n_xw_w  = 96*DI_;       // 196,608
    const int n_dtw_w = DI_*DTR_;     // 131,072
    const int t0c = n_in_w>>2;
    const int t1c = t0c + (n_ow_w>>2);
    const int t2c = t1c + (n_xw_w>>2);
    const int t3c = t2c + (n_dtw_w>>2);   // 1,654,784
    const int cvtBlocks = (t3c+255)/256;  // 6464
    const int prepGrid  = MROWS + cvtBlocks;

    for (int l = 0; l < NL_; l++){
        const float* nw_l  = norm_w + l*H_;
        const float* cw_l  = cw     + l*DI_*4;
        const float* cb_l  = cb     + l*DI_;
        const float* dtb_l = dtb    + l*DI_;
        const float* al_l  = A_log  + l*DI_*DS_;
        const float* Dp_l  = Dp     + l*DI_;

        // fused: (embed if l==0) + rmsnorm + per-layer weight cvt4
        prep_kernel<<<prepGrid, 256, 0, stream>>>(
            (l == 0) ? ids : nullptr, emb, h, nw_l, xn,
            in_w + (size_t)l*n_in_w, wb_in, t0c,
            ow   + (size_t)l*n_ow_w, wb_ow, t1c,
            xw   + (size_t)l*n_xw_w, wb_xw, t2c,
            dtw  + (size_t)l*n_dtw_w, wb_dtw, t3c);

        // xz = xn @ in_w^T   (4096x4096x1024) -> bf16 row-major
        gemm_bt<<<dim3(32,32), 256, 0, stream>>>(xn, H_, wb_in, H_,
                                                 MROWS, 2*DI_, H_,
                                                 nullptr, xz, 2*DI_, nullptr, 3);
        // conv+silu: u row-major (overwrites xn/wb_in region) + u_t time-major
        conv_silu_kernel<<<dim3(MROWS/64, DI_/64), 256, 0, stream>>>(xz, cw_l, cb_l, u, u_t);
        // ssm = u @ xw^T (N=96): dtA row-major, B/C transposed -- 256 blocks (N split, static)
        gemm_ssm<<<dim3(128,2), 256, 0, stream>>>(u, wb_xw, dtA, sB_t, sC_t);
        // dt_t = softplus(dtA @ dtw^T + dtb), stored TRANSPOSED [d][bt]
        gemm_bt<<<dim3(16,32), 256, 0, stream>>>(dtA, DTR_, wb_dtw, DTR_,
                                                 MROWS, DI_, DTR_,
                                                 nullptr, dt_t, MROWS, dtb_l, 1);
        // scan (time-vectorized x8, fused-DPP reduce, depth-4 prefetch) -> y_t [d][bt]
        scan_kernel<<<512, 256, 0, stream>>>(dt_t, u_t, sB_t, sC_t, al_l, Dp_l, y_t);
        // gate+transpose: xz[:, :DI] = y * silu(z)
        gate_kernel<<<dim3(MROWS/64, DI_/64), 256, 0, stream>>>(y_t, xz);
        // h += y_gated @ ow^T  (A = xz x-half, lda=4096); BN=64 -> 512 blocks, 2/CU
        gemm_out<<<dim3(16,32), 256, 0, stream>>>(xz, 2*DI_, wb_ow, DI_,
                                                  DI_, MROWS, h, H_, nullptr, 2);
    }

    // fused: featnorm (with inline pos) + head projw convert
    tail_kernel<<<B_*KTOK + ((LLM_*H_/4)+255)/256, 256, 0, stream>>>(
        h, fnw, ids, fe, projw, wb_in, LLM_*H_/4);
    // head: out = fe @ wb_in^T + projb   (M=64, N=4096, K=1024) -> 64 blocks
    gemm_out<<<dim3(LLM_/64,1), 256, 0, stream>>>(fe, H_, wb_in, H_,
                                                  H_, B_*KTOK, out, LLM_, projb, 0);
}

// Round 10
// 1320.969 us; speedup vs baseline: 1.2089x; 1.2089x over previous
//
#include <hip/hip_runtime.h>
#include <hip/hip_bf16.h>
#include <cstdint>
#include <cstddef>

// Problem constants
#define H_    1024
#define DI_   2048
#define DS_   16
#define DTR_  64
#define NL_   4
#define LLM_  4096
#define B_    4
#define L_    1024
#define MEMID 50279
#define KTOK  16
#define MROWS (B_*L_)   // 4096
#define BK    64

using bf16 = __hip_bfloat16;
typedef __attribute__((ext_vector_type(8))) short short8;
typedef __attribute__((ext_vector_type(4))) short short4v;
typedef __attribute__((ext_vector_type(4))) float floatx4;
typedef __attribute__((ext_vector_type(4))) unsigned int uint4v;

__device__ __forceinline__ float b2f(bf16 v){ return __bfloat162float(v); }
__device__ __forceinline__ bf16  f2b(float v){ return __float2bfloat16(v); }
__device__ __forceinline__ float sh2f(short s){
    unsigned u = ((unsigned)(unsigned short)s) << 16;
    return __builtin_bit_cast(float, u);
}
__device__ __forceinline__ short f2sh(float v){
    bf16 b = f2b(v);
    return __builtin_bit_cast(short, b);
}
__device__ __forceinline__ float bcf(unsigned int u){ return __builtin_bit_cast(float, u); }

// fused-DPP 16-lane row sum; result valid in lane 15 of each 16-lane row
__device__ __forceinline__ float rowsum16(float v){
    float t;
    asm("v_add_f32_dpp %0, %1, %1 row_shr:1 row_mask:0xf bank_mask:0xf bound_ctrl:0" : "=v"(t) : "v"(v));
    asm("v_add_f32_dpp %0, %1, %1 row_shr:2 row_mask:0xf bank_mask:0xf bound_ctrl:0" : "=v"(v) : "v"(t));
    asm("v_add_f32_dpp %0, %1, %1 row_shr:4 row_mask:0xf bank_mask:0xf bound_ctrl:0" : "=v"(t) : "v"(v));
    asm("v_add_f32_dpp %0, %1, %1 row_shr:8 row_mask:0xf bank_mask:0xf bound_ctrl:0" : "=v"(v) : "v"(t));
    return v;
}

// async global->LDS, 16B per lane; LDS dest = wave-uniform base + lane*16
__device__ __forceinline__ void async16(bf16* l, const bf16* g){
    __builtin_amdgcn_global_load_lds(
        (const __attribute__((address_space(1))) void*)g,
        (__attribute__((address_space(3))) void*)l,
        16, 0, 0);
}

// fast softplus: ln(1+e^x) via native v_exp_f32/v_log_f32 (~5 instrs).
// log1pf's precise libm path (~250 serially-dependent instrs) made the
// dt-projection epilogue latency-bound: 122 us @ MfmaUtil 0.33% (round-9 PMC).
__device__ __forceinline__ float softplus_fast(float x){
    return (x > 20.f) ? x : __logf(1.f + __expf(x));
}

// ---------------- fused prep: cvt4 (per-layer weights) + rmsnorm (+ embed when ids!=null)
// blocks [0, MROWS): (embed row if ids) + rmsnorm row -> xn
// blocks [MROWS, MROWS+6464): 4-segment f32->bf16 weight convert
__global__ void prep_kernel(const int* __restrict__ ids,
                            const float* __restrict__ emb,
                            float* __restrict__ h,
                            const float* __restrict__ nw,
                            bf16* __restrict__ xn,
                            const float* __restrict__ s0, bf16* __restrict__ d0, int t0,
                            const float* __restrict__ s1, bf16* __restrict__ d1, int t1,
                            const float* __restrict__ s2, bf16* __restrict__ d2, int t2,
                            const float* __restrict__ s3, bf16* __restrict__ d3, int t3)
{
    int bid = blockIdx.x;
    if (bid < MROWS){
        float4 v;
        if (ids){
            int id = ids[bid];
            v = ((const float4*)(emb + (size_t)id * H_))[threadIdx.x];
            ((float4*)(h + (size_t)bid * H_))[threadIdx.x] = v;
        } else {
            v = ((const float4*)(h + (size_t)bid * H_))[threadIdx.x];
        }
        float ss = v.x*v.x + v.y*v.y + v.z*v.z + v.w*v.w;
        #pragma unroll
        for (int off = 32; off; off >>= 1) ss += __shfl_down(ss, off, 64);
        __shared__ float red[4];
        __shared__ float scale_s;
        int lane = threadIdx.x & 63, wv = threadIdx.x >> 6;
        if (lane == 0) red[wv] = ss;
        __syncthreads();
        if (threadIdx.x == 0){
            float t = red[0]+red[1]+red[2]+red[3];
            scale_s = rsqrtf(t * (1.f/H_) + 1e-5f);
        }
        __syncthreads();
        float sc = scale_s;
        float4 w4 = ((const float4*)nw)[threadIdx.x];
        short4v o;
        o[0] = f2sh(v.x * sc * w4.x);
        o[1] = f2sh(v.y * sc * w4.y);
        o[2] = f2sh(v.z * sc * w4.z);
        o[3] = f2sh(v.w * sc * w4.w);
        ((short4v*)(xn + (size_t)bid*H_))[threadIdx.x] = o;
    } else {
        int i = (bid - MROWS)*256 + threadIdx.x;      // float4 index
        const float* s; bf16* d; int local;
        if      (i < t0){ s=s0; d=d0; local=i; }
        else if (i < t1){ s=s1; d=d1; local=i-t0; }
        else if (i < t2){ s=s2; d=d2; local=i-t1; }
        else if (i < t3){ s=s3; d=d3; local=i-t2; }
        else return;
        float4 f = ((const float4*)s)[local];
        short4v o; o[0]=f2sh(f.x); o[1]=f2sh(f.y); o[2]=f2sh(f.z); o[3]=f2sh(f.w);
        ((short4v*)d)[local] = o;
    }
}

// ---------------- MFMA GEMM, LDS-staged, BK=64, XOR-swizzled LDS (T2):
// staging pre-permutes the GLOBAL source column-block so linear global_load_lds
// dests receive swizzled content; ds_read XORs the block index with (row&7).
// C[m,n] = sum_k A[m,k]*B[n,k]
// mode 1: Cb[n*ldc+m] = bf16(softplus(acc+bias[n]))   TRANSPOSED (dt_t)
// mode 3: Cb[m*ldc+n] = bf16(acc)                (row-major)
__launch_bounds__(256)
__global__ void gemm_bt(const bf16* __restrict__ A, int lda,
                        const bf16* __restrict__ Bm, int ldb,
                        int M, int N, int K,
                        float* __restrict__ Cf, bf16* __restrict__ Cb, int ldc,
                        const float* __restrict__ bias, int mode)
{
    __shared__ __align__(16) bf16 sA[128*BK];   // 16 KB
    __shared__ __align__(16) bf16 sB[128*BK];   // 16 KB

    int tid  = threadIdx.x;
    int lane = tid & 63;
    int wv   = tid >> 6;          // 4 waves, 2x2 of 64x64
    int quad = lane >> 4, r16 = lane & 15;
    int m0 = blockIdx.y*128, n0 = blockIdx.x*128;
    int wm = (wv>>1)*64, wn = (wv&1)*64;

    int rr = tid >> 3;                         // 0..31
    int kc = ((tid & 7) ^ (rr & 7)) * 8;       // swizzled source col-block
    const bf16* pA = A  + (size_t)(m0 + rr)*lda + kc;
    const bf16* pB = Bm + (size_t)(n0 + rr)*ldb + kc;
    bf16* lA = sA + wv*512;
    bf16* lB = sB + wv*512;

    floatx4 acc[4][4];
    #pragma unroll
    for (int i=0;i<4;i++)
        #pragma unroll
        for (int j=0;j<4;j++) acc[i][j] = (floatx4){0.f,0.f,0.f,0.f};

    for (int k0 = 0; k0 < K; k0 += BK){
        async16(lA,        pA);
        async16(lA + 2048, pA + (size_t)32*lda);
        async16(lA + 4096, pA + (size_t)64*lda);
        async16(lA + 6144, pA + (size_t)96*lda);
        async16(lB,        pB);
        async16(lB + 2048, pB + (size_t)32*ldb);
        async16(lB + 4096, pB + (size_t)64*ldb);
        async16(lB + 6144, pB + (size_t)96*ldb);
        pA += BK; pB += BK;
        __syncthreads();

        #pragma unroll
        for (int kk=0; kk<2; kk++){
            short8 a[4], b[4];
            #pragma unroll
            for (int i=0;i<4;i++)
                a[i] = *(const short8*)(sA + (wm + i*16 + r16)*BK
                                          + (((kk*4+quad) ^ (r16 & 7))*8));
            #pragma unroll
            for (int j=0;j<4;j++)
                b[j] = *(const short8*)(sB + (wn + j*16 + r16)*BK
                                          + (((kk*4+quad) ^ (r16 & 7))*8));
            #pragma unroll
            for (int i=0;i<4;i++)
                #pragma unroll
                for (int j=0;j<4;j++)
                    acc[i][j] = __builtin_amdgcn_mfma_f32_16x16x32_bf16(a[i], b[j], acc[i][j], 0, 0, 0);
        }
        __syncthreads();
    }

    #pragma unroll
    for (int i=0;i<4;i++)
        #pragma unroll
        for (int j=0;j<4;j++){
            int mq = m0 + wm + i*16 + quad*4;
            int n  = n0 + wn + j*16 + r16;
            if (mode == 1){
                if (n < N){
                    short4v pk;
                    #pragma unroll
                    for (int rr2=0;rr2<4;rr2++){
                        float xx = acc[i][j][rr2] + bias[n];
                        pk[rr2] = f2sh(softplus_fast(xx));
                    }
                    *(short4v*)(Cb + (size_t)n*ldc + mq) = pk;
                }
            } else {
                #pragma unroll
                for (int rr2=0;rr2<4;rr2++){
                    int m = mq + rr2;
                    if (m < M && n < N)
                        Cb[(size_t)m*ldc + n] = f2b(acc[i][j][rr2]);
                }
            }
        }
}

// ---------------- out-proj / head GEMM: BM=128, BN=64, XOR-swizzled LDS.
// mode 2: Cf[m*ldc+n] += acc (unguarded, M multiple of 128)
// mode 0: if (m<M) Cf[m*ldc+n] = acc + bias[n]
__launch_bounds__(256)
__global__ void gemm_out(const bf16* __restrict__ A, int lda,
                         const bf16* __restrict__ Bm, int ldb,
                         int K, int M,
                         float* __restrict__ Cf, int ldc,
                         const float* __restrict__ bias, int mode)
{
    __shared__ __align__(16) bf16 sA[128*BK];   // 16 KB
    __shared__ __align__(16) bf16 sB[64*BK];    //  8 KB

    int tid  = threadIdx.x;
    int lane = tid & 63;
    int wv   = tid >> 6;           // 4 waves, 2x2 of 64x32
    int quad = lane >> 4, r16 = lane & 15;
    int m0 = blockIdx.y*128, n0 = blockIdx.x*64;
    int wm = (wv>>1)*64, wn = (wv&1)*32;

    int rr = tid >> 3;                         // 0..31
    int kc = ((tid & 7) ^ (rr & 7)) * 8;       // swizzled source col-block
    const bf16* pA = A  + (size_t)(m0 + rr)*lda + kc;
    const bf16* pB = Bm + (size_t)(n0 + rr)*ldb + kc;
    bf16* lA = sA + wv*512;
    bf16* lB = sB + wv*512;

    floatx4 acc[4][2];
    #pragma unroll
    for (int i=0;i<4;i++)
        #pragma unroll
        for (int j=0;j<2;j++) acc[i][j] = (floatx4){0.f,0.f,0.f,0.f};

    for (int k0 = 0; k0 < K; k0 += BK){
        async16(lA,        pA);
        async16(lA + 2048, pA + (size_t)32*lda);
        async16(lA + 4096, pA + (size_t)64*lda);
        async16(lA + 6144, pA + (size_t)96*lda);
        async16(lB,        pB);
        async16(lB + 2048, pB + (size_t)32*ldb);
        pA += BK; pB += BK;
        __syncthreads();

        #pragma unroll
        for (int kk=0; kk<2; kk++){
            short8 a[4], b[2];
            #pragma unroll
            for (int i=0;i<4;i++)
                a[i] = *(const short8*)(sA + (wm + i*16 + r16)*BK
                                          + (((kk*4+quad) ^ (r16 & 7))*8));
            #pragma unroll
            for (int j=0;j<2;j++)
                b[j] = *(const short8*)(sB + (wn + j*16 + r16)*BK
                                          + (((kk*4+quad) ^ (r16 & 7))*8));
            #pragma unroll
            for (int i=0;i<4;i++)
                #pragma unroll
                for (int j=0;j<2;j++)
                    acc[i][j] = __builtin_amdgcn_mfma_f32_16x16x32_bf16(a[i], b[j], acc[i][j], 0, 0, 0);
        }
        __syncthreads();
    }

    #pragma unroll
    for (int i=0;i<4;i++)
        #pragma unroll
        for (int j=0;j<2;j++){
            int mq = m0 + wm + i*16 + quad*4;
            int n  = n0 + wn + j*16 + r16;
            if (mode == 2){
                #pragma unroll
                for (int rr2=0;rr2<4;rr2++)
                    Cf[(size_t)(mq+rr2)*ldc + n] += acc[i][j][rr2];
            } else {
                #pragma unroll
                for (int rr2=0;rr2<4;rr2++){
                    int m = mq + rr2;
                    if (m < M)
                        Cf[(size_t)m*ldc + n] = acc[i][j][rr2] + bias[n];
                }
            }
        }
}

// ---------------- specialized ssm GEMM: M=4096, N=96, K=2048, BM=32
// grid (128, 2): blockIdx.y=0 -> cols 0..63 (dtA), blockIdx.y=1 -> cols 64..95 (B/C).
// FULLY STATIC per-branch code (rule #20).
__launch_bounds__(256)
__global__ void gemm_ssm(const bf16* __restrict__ A,    // u, lda = DI_
                         const bf16* __restrict__ Bm,   // wb_xw, ldb = DI_
                         bf16* __restrict__ dtA,
                         bf16* __restrict__ pBt,
                         bf16* __restrict__ pCt)
{
    __shared__ __align__(16) bf16 sA2[32*64];   // 4 KB
    __shared__ __align__(16) bf16 sB2[64*64];   // 8 KB

    int tid  = threadIdx.x;
    int lane = tid & 63;
    int wv   = tid >> 6;           // 4 waves: 2x2
    int quad = lane >> 4, r16 = lane & 15;
    int m0 = blockIdx.x * 32;
    int wr = wv >> 1, wc = wv & 1;

    int ar = tid >> 3;                          // 0..31
    int kc = ((tid & 7) ^ (ar & 7)) * 8;        // swizzled source col-block
    const bf16* pA  = A  + (size_t)(m0 + ar)*DI_ + kc;
    bf16* lA  = sA2 + wv*512;

    if (blockIdx.y == 0){
        // cols 0..63 -> dtA; each wave does 2 static n-frags at wc*32 + {0,16}
        const bf16* pB0 = Bm + (size_t)(ar)     *DI_ + kc;
        const bf16* pB1 = Bm + (size_t)(32 + ar)*DI_ + kc;
        bf16* lB0 = sB2 + wv*512;
        bf16* lB1 = sB2 + 2048 + wv*512;
        floatx4 acc0 = (floatx4){0.f,0.f,0.f,0.f};
        floatx4 acc1 = (floatx4){0.f,0.f,0.f,0.f};
        for (int k0 = 0; k0 < DI_; k0 += 64){
            async16(lA,  pA);
            async16(lB0, pB0);
            async16(lB1, pB1);
            pA += 64; pB0 += 64; pB1 += 64;
            __syncthreads();
            #pragma unroll
            for (int kk=0; kk<2; kk++){
                int swz = ((kk*4+quad) ^ (r16 & 7))*8;
                short8 a  = *(const short8*)(sA2 + (wr*16 + r16)*64 + swz);
                short8 b0 = *(const short8*)(sB2 + (wc*32 + r16)*64 + swz);
                short8 b1 = *(const short8*)(sB2 + (wc*32 + 16 + r16)*64 + swz);
                acc0 = __builtin_amdgcn_mfma_f32_16x16x32_bf16(a, b0, acc0, 0, 0, 0);
                acc1 = __builtin_amdgcn_mfma_f32_16x16x32_bf16(a, b1, acc1, 0, 0, 0);
            }
            __syncthreads();
        }
        int mq = m0 + wr*16 + quad*4;
        int na = wc*32 + r16;
        int nb = wc*32 + 16 + r16;
        #pragma unroll
        for (int rr2=0;rr2<4;rr2++){
            dtA[(size_t)(mq+rr2)*64 + na] = f2b(acc0[rr2]);
            dtA[(size_t)(mq+rr2)*64 + nb] = f2b(acc1[rr2]);
        }
    } else {
        // cols 64..95 -> pBt (wc=0) / pCt (wc=1); 1 static n-frag per wave
        const bf16* pBs = Bm + (size_t)(64 + ar)*DI_ + kc;
        bf16* lB0 = sB2 + wv*512;
        floatx4 acc0 = (floatx4){0.f,0.f,0.f,0.f};
        for (int k0 = 0; k0 < DI_; k0 += 64){
            async16(lA,  pA);
            async16(lB0, pBs);
            pA += 64; pBs += 64;
            __syncthreads();
            #pragma unroll
            for (int kk=0; kk<2; kk++){
                int swz = ((kk*4+quad) ^ (r16 & 7))*8;
                short8 a  = *(const short8*)(sA2 + (wr*16 + r16)*64 + swz);
                short8 b0 = *(const short8*)(sB2 + (wc*16 + r16)*64 + swz);
                acc0 = __builtin_amdgcn_mfma_f32_16x16x32_bf16(a, b0, acc0, 0, 0, 0);
            }
            __syncthreads();
        }
        int mq = m0 + wr*16 + quad*4;
        short4v pk;
        #pragma unroll
        for (int rr2=0;rr2<4;rr2++) pk[rr2] = f2sh(acc0[rr2]);
        if (wc == 0) *(short4v*)(pBt + (size_t)r16*MROWS + mq) = pk;
        else         *(short4v*)(pCt + (size_t)r16*MROWS + mq) = pk;
    }
}

// ---------------- causal depthwise conv (k=4) + silu, vectorized short8;
// writes u (row-major) and u_t ([d][bt])
__global__ void conv_silu_kernel(const bf16* __restrict__ xz,
                                 const float* __restrict__ cw,
                                 const float* __restrict__ cb,
                                 bf16* __restrict__ u,
                                 bf16* __restrict__ u_t)
{
    __shared__ float tile[64][65];
    int bt0 = blockIdx.x * 64;
    int d0  = blockIdx.y * 64;
    int tid = threadIdx.x;
    const short8 z8 = {0,0,0,0,0,0,0,0};
    #pragma unroll
    for (int it = 0; it < 2; it++){
        int task = it*256 + tid;        // 0..511
        int g    = task & 7;            // d-group (8 channels)
        int tr   = task >> 3;           // 0..63
        int row  = bt0 + tr;
        int t    = row & (L_-1);
        int d8   = d0 + g*8;
        const bf16* base = xz + (size_t)row*(2*DI_) + d8;
        short8 x3 = *(const short8*)(base);
        short8 x2 = (t>=1) ? *(const short8*)(base - 1*(2*DI_)) : z8;
        short8 x1 = (t>=2) ? *(const short8*)(base - 2*(2*DI_)) : z8;
        short8 x0 = (t>=3) ? *(const short8*)(base - 3*(2*DI_)) : z8;
        short8 out;
        #pragma unroll
        for (int j=0;j<8;j++){
            int d = d8 + j;
            float4 w4 = ((const float4*)cw)[d];
            float acc = cb[d];
            acc += sh2f(x0[j])*w4.x;
            acc += sh2f(x1[j])*w4.y;
            acc += sh2f(x2[j])*w4.z;
            acc += sh2f(x3[j])*w4.w;
            float s = acc / (1.f + __expf(-acc));
            out[j] = f2sh(s);
            tile[g*8+j][tr] = s;
        }
        *(short8*)(u + (size_t)row*DI_ + d8) = out;
    }
    __syncthreads();
    #pragma unroll
    for (int it = 0; it < 2; it++){
        int task = it*256 + tid;
        int g    = task & 7;            // t-group (8 timesteps)
        int dr   = task >> 3;           // 0..63
        int tc8  = g*8;
        short8 o;
        #pragma unroll
        for (int j=0;j<8;j++) o[j] = f2sh(tile[dr][tc8+j]);
        *(short8*)(u_t + (size_t)(d0+dr)*MROWS + bt0 + tc8) = o;
    }
}

// ---------------- selective scan, time-vectorized x8, fused-DPP reduce,
// depth-4 rotating register prefetch (statically indexed, unclamped —
// tail over-reads stay inside the workspace and are never consumed),
// dword bf16 decode, cvt_pk pack
#define SCAN_GROUP(dtv,uv,bv,cv,gidx) { \
    uint4v yo; \
    _Pragma("unroll") \
    for (int j = 0; j < 4; j++){ \
        unsigned int wdt = (dtv)[j], wu = (uv)[j], wB = (bv)[j], wC = (cv)[j]; \
        float dt0 = bcf(wdt << 16), u0 = bcf(wu << 16); \
        float b0  = bcf(wB  << 16), c0 = bcf(wC << 16); \
        float e0; asm("v_exp_f32 %0, %1" : "=v"(e0) : "v"(dt0 * A2)); \
        state = __builtin_fmaf(state, e0, dt0 * u0 * b0); \
        float y0 = __builtin_fmaf(u0, Dv, rowsum16(state * c0)); \
        float dt1 = bcf(wdt & 0xffff0000u), u1 = bcf(wu & 0xffff0000u); \
        float b1  = bcf(wB  & 0xffff0000u), c1 = bcf(wC & 0xffff0000u); \
        float e1; asm("v_exp_f32 %0, %1" : "=v"(e1) : "v"(dt1 * A2)); \
        state = __builtin_fmaf(state, e1, dt1 * u1 * b1); \
        float y1 = __builtin_fmaf(u1, Dv, rowsum16(state * c1)); \
        unsigned int pk; \
        asm("v_cvt_pk_bf16_f32 %0, %1, %2" : "=v"(pk) : "v"(y0), "v"(y1)); \
        yo[j] = pk; \
    } \
    if (s_idx == 15) yp_[gidx] = yo; \
}

__global__ void scan_kernel(const bf16* __restrict__ dt_t,
                            const bf16* __restrict__ u_t,
                            const bf16* __restrict__ sB_t,
                            const bf16* __restrict__ sC_t,
                            const float* __restrict__ A_log,
                            const float* __restrict__ Dp,
                            bf16* __restrict__ y_t)
{
    int lane  = threadIdx.x & 63;
    int wv    = threadIdx.x >> 6;
    int s_idx = lane & 15;
    int ch    = lane >> 4;
    int c = blockIdx.x*16 + wv*4 + ch;      // 0..8191 channel (b,d)
    int d = c & (DI_-1);
    int b = c >> 11;
    // pre-scale A by log2(e): per-step decay uses v_exp_f32 (2^x) directly
    float A2 = -__expf(A_log[d*DS_ + s_idx]) * 1.4426950408889634f;
    float Dv = Dp[d];
    const uint4v* dtp = (const uint4v*)(dt_t + (size_t)d*MROWS + b*L_);
    const uint4v* utp = (const uint4v*)(u_t  + (size_t)d*MROWS + b*L_);
    const uint4v* Bp  = (const uint4v*)(sB_t + (size_t)s_idx*MROWS + b*L_);
    const uint4v* Cp  = (const uint4v*)(sC_t + (size_t)s_idx*MROWS + b*L_);
    uint4v* yp_ = (uint4v*)(y_t + (size_t)d*MROWS + b*L_);

    const int NG = L_/8;   // 128 groups of 8 timesteps
    float state = 0.f;

    // depth-4 rotating prefetch (all indices static; NG % 4 == 0)
    uint4v dA = dtp[0], uA = utp[0], bA = Bp[0], cA = Cp[0];
    uint4v dB = dtp[1], uB = utp[1], bB = Bp[1], cB = Cp[1];
    uint4v dC = dtp[2], uC = utp[2], bC = Bp[2], cC = Cp[2];
    uint4v dD = dtp[3], uD = utp[3], bD = Bp[3], cD = Cp[3];

    for (int g = 0; g < NG; g += 4){
        SCAN_GROUP(dA, uA, bA, cA, g);
        dA = dtp[g+4]; uA = utp[g+4]; bA = Bp[g+4]; cA = Cp[g+4];
        SCAN_GROUP(dB, uB, bB, cB, g+1);
        dB = dtp[g+5]; uB = utp[g+5]; bB = Bp[g+5]; cB = Cp[g+5];
        SCAN_GROUP(dC, uC, bC, cC, g+2);
        dC = dtp[g+6]; uC = utp[g+6]; bC = Bp[g+6]; cC = Cp[g+6];
        SCAN_GROUP(dD, uD, bD, cD, g+3);
        dD = dtp[g+7]; uD = utp[g+7]; bD = Bp[g+7]; cD = Cp[g+7];
    }
}

// ---------------- gate + transpose, vectorized short8: xz[:, :DI] = y * silu(z)
__global__ void gate_kernel(const bf16* __restrict__ y_t,
                            bf16* __restrict__ xz)
{
    __shared__ float tile[64][65];
    int bt0 = blockIdx.x * 64;
    int d0  = blockIdx.y * 64;
    int tid = threadIdx.x;
    #pragma unroll
    for (int it = 0; it < 2; it++){
        int task = it*256 + tid;        // 0..511
        int g    = task & 7;            // bt-group (8 timesteps)
        int dr   = task >> 3;           // 0..63
        short8 v = *(const short8*)(y_t + (size_t)(d0+dr)*MROWS + bt0 + g*8);
        #pragma unroll
        for (int j=0;j<8;j++) tile[dr][g*8+j] = sh2f(v[j]);
    }
    __syncthreads();
    #pragma unroll
    for (int it = 0; it < 2; it++){
        int task = it*256 + tid;
        int g    = task & 7;            // d-group (8 channels)
        int tr   = task >> 3;           // 0..63
        int row  = bt0 + tr;
        int d8   = g*8;
        short8 z8 = *(const short8*)(xz + (size_t)row*(2*DI_) + DI_ + d0 + d8);
        short8 o;
        #pragma unroll
        for (int j=0;j<8;j++){
            float z  = sh2f(z8[j]);
            float sz = z / (1.f + __expf(-z));
            o[j] = f2sh(tile[d8+j][tr] * sz);
        }
        *(short8*)(xz + (size_t)row*(2*DI_) + d0 + d8) = o;
    }
}

// ---------------- tail: featnorm with inline pos recompute (blocks 0..63)
//                  + head projw f32->bf16 convert (blocks 64..)
__global__ void tail_kernel(const float* __restrict__ h,
                            const float* __restrict__ w,
                            const int* __restrict__ ids,
                            bf16* __restrict__ feats,
                            const float* __restrict__ projw,
                            bf16* __restrict__ wb, int n4)
{
    if (blockIdx.x < B_*KTOK){
        int bk = blockIdx.x;
        int b = bk >> 4, k = bk & 15;
        int t = threadIdx.x;
        __shared__ int cnt[256];
        __shared__ int pos_s;
        int local = 0;
        #pragma unroll
        for (int i=0;i<4;i++)
            if (ids[b*L_ + t*4 + i] == MEMID) local++;
        cnt[t] = local;
        __syncthreads();
        if (t == 0){
            int run = 0;
            for (int i=0;i<256;i++){ int tmp = cnt[i]; cnt[i] = run; run += tmp; }
        }
        __syncthreads();
        int rank = cnt[t];
        #pragma unroll
        for (int i=0;i<4;i++){
            int l = t*4 + i;
            if (ids[b*L_ + l] == MEMID){
                if (rank == k) pos_s = l;
                rank++;
            }
        }
        __syncthreads();
        int row = b*L_ + pos_s;
        float4 v = ((const float4*)(h + (size_t)row * H_))[t];
        float ss = v.x*v.x + v.y*v.y + v.z*v.z + v.w*v.w;
        #pragma unroll
        for (int off = 32; off; off >>= 1) ss += __shfl_down(ss, off, 64);
        __shared__ float red[4];
        __shared__ float scale_s;
        int lane = t & 63, wv = t >> 6;
        if (lane == 0) red[wv] = ss;
        __syncthreads();
        if (t == 0){
            float tt = red[0]+red[1]+red[2]+red[3];
            scale_s = rsqrtf(tt * (1.f/H_) + 1e-5f);
        }
        __syncthreads();
        float sc = scale_s;
        float4 w4 = ((const float4*)w)[t];
        short4v o;
        o[0] = f2sh(v.x * sc * w4.x);
        o[1] = f2sh(v.y * sc * w4.y);
        o[2] = f2sh(v.z * sc * w4.z);
        o[3] = f2sh(v.w * sc * w4.w);
        ((short4v*)(feats + (size_t)bk*H_))[t] = o;
    } else {
        int i = (blockIdx.x - B_*KTOK)*256 + threadIdx.x;
        if (i < n4){
            float4 f = ((const float4*)projw)[i];
            short4v o; o[0]=f2sh(f.x); o[1]=f2sh(f.y); o[2]=f2sh(f.z); o[3]=f2sh(f.w);
            ((short4v*)wb)[i] = o;
        }
    }
}

extern "C" void kernel_launch(void* const* d_in, const int* in_sizes, int n_in,
                              void* d_out, int out_size, void* d_ws, size_t ws_size,
                              hipStream_t stream)
{
    const int*   ids    = (const int*)  d_in[0];
    const float* emb    = (const float*)d_in[1];
    const float* norm_w = (const float*)d_in[2];
    const float* in_w   = (const float*)d_in[3];
    const float* cw     = (const float*)d_in[4];
    const float* cb     = (const float*)d_in[5];
    const float* xw     = (const float*)d_in[6];
    const float* dtw    = (const float*)d_in[7];
    const float* dtb    = (const float*)d_in[8];
    const float* A_log  = (const float*)d_in[9];
    const float* Dp     = (const float*)d_in[10];
    const float* ow     = (const float*)d_in[11];
    const float* fnw    = (const float*)d_in[12];
    const float* projw  = (const float*)d_in[13];
    const float* projb  = (const float*)d_in[14];
    float* out          = (float*)d_out;

    // workspace layout (bytes); total = 106,430,720 (known-good)
    char* ws = (char*)d_ws;
    float* h     = (float*)(ws + 0);             // 16.78 MB
    bf16*  xn    = (bf16*) (ws + 16777216);      //  8.39 MB
    bf16*  wb_in = (bf16*) (ws + 25165824);      //  8.39 MB (also: head proj bf16)
    bf16*  u     = (bf16*) (ws + 16777216);      // 16.78 MB overlay (xn+wb_in)
    bf16*  dt_t  = (bf16*) (ws + 16777216);      // 16.78 MB overlay (same)
    bf16*  xz    = (bf16*) (ws + 33554432);      // 33.55 MB
    bf16*  u_t   = (bf16*) (ws + 67108864);      // 16.78 MB
    bf16*  y_t   = (bf16*) (ws + 83886080);      // 16.78 MB
    bf16*  dtA   = (bf16*) (ws + 100663296);     //  0.52 MB (4096x64)
    bf16*  sB_t  = (bf16*) (ws + 101187584);     //  0.13 MB (16x4096)
    bf16*  sC_t  = (bf16*) (ws + 101318656);     //  0.13 MB
    bf16*  fe    = (bf16*) (ws + 101449728);     //  0.13 MB
    int*   pos   = (int*)  (ws + 101580800);     //  256 B (unused now)
    bf16*  wb_ow = (bf16*) (ws + 101581056);     //  4.19 MB
    bf16*  wb_xw = (bf16*) (ws + 105775360);     //  0.39 MB
    bf16*  wb_dtw= (bf16*) (ws + 106168576);     //  0.26 MB -> end 106430720
    (void)pos;

    const int n_in_w  = 2*DI_*H_;     // 4,194,304
    const int n_ow_w  = H_*DI_;       // 2,097,152
    const int n_xw_w  = 96*DI_;       // 196,608
    const int n_dtw_w = DI_*DTR_;     // 131,072
    const int t0c = n_in_w>>2;
    const int t1c = t0c + (n_ow_w>>2);
    const int t2c = t1c + (n_xw_w>>2);
    const int t3c = t2c + (n_dtw_w>>2);   // 1,654,784
    const int cvtBlocks = (t3c+255)/256;  // 6464
    const int prepGrid  = MROWS + cvtBlocks;

    for (int l = 0; l < NL_; l++){
        const float* nw_l  = norm_w + l*H_;
        const float* cw_l  = cw     + l*DI_*4;
        const float* cb_l  = cb     + l*DI_;
        const float* dtb_l = dtb    + l*DI_;
        const float* al_l  = A_log  + l*DI_*DS_;
        const float* Dp_l  = Dp     + l*DI_;

        // fused: (embed if l==0) + rmsnorm + per-layer weight cvt4
        prep_kernel<<<prepGrid, 256, 0, stream>>>(
            (l == 0) ? ids : nullptr, emb, h, nw_l, xn,
            in_w + (size_t)l*n_in_w, wb_in, t0c,
            ow   + (size_t)l*n_ow_w, wb_ow, t1c,
            xw   + (size_t)l*n_xw_w, wb_xw, t2c,
            dtw  + (size_t)l*n_dtw_w, wb_dtw, t3c);

        // xz = xn @ in_w^T   (4096x4096x1024) -> bf16 row-major
        gemm_bt<<<dim3(32,32), 256, 0, stream>>>(xn, H_, wb_in, H_,
                                                 MROWS, 2*DI_, H_,
                                                 nullptr, xz, 2*DI_, nullptr, 3);
        // conv+silu: u row-major (overwrites xn/wb_in region) + u_t time-major
        conv_silu_kernel<<<dim3(MROWS/64, DI_/64), 256, 0, stream>>>(xz, cw_l, cb_l, u, u_t);
        // ssm = u @ xw^T (N=96): dtA row-major, B/C transposed -- 256 blocks (N split, static)
        gemm_ssm<<<dim3(128,2), 256, 0, stream>>>(u, wb_xw, dtA, sB_t, sC_t);
        // dt_t = softplus(dtA @ dtw^T + dtb), stored TRANSPOSED [d][bt] (fast softplus)
        gemm_bt<<<dim3(16,32), 256, 0, stream>>>(dtA, DTR_, wb_dtw, DTR_,
                                                 MROWS, DI_, DTR_,
                                                 nullptr, dt_t, MROWS, dtb_l, 1);
        // scan (time-vectorized x8, fused-DPP reduce, depth-4 prefetch) -> y_t [d][bt]
        scan_kernel<<<512, 256, 0, stream>>>(dt_t, u_t, sB_t, sC_t, al_l, Dp_l, y_t);
        // gate+transpose: xz[:, :DI] = y * silu(z)
        gate_kernel<<<dim3(MROWS/64, DI_/64), 256, 0, stream>>>(y_t, xz);
        // h += y_gated @ ow^T  (A = xz x-half, lda=4096); BN=64 -> 512 blocks, 2/CU
        gemm_out<<<dim3(16,32), 256, 0, stream>>>(xz, 2*DI_, wb_ow, DI_,
                                                  DI_, MROWS, h, H_, nullptr, 2);
    }

    // fused: featnorm (with inline pos) + head projw convert
    tail_kernel<<<B_*KTOK + ((LLM_*H_/4)+255)/256, 256, 0, stream>>>(
        h, fnw, ids, fe, projw, wb_in, LLM_*H_/4);
    // head: out = fe @ wb_in^T + projb   (M=64, N=4096, K=1024) -> 64 blocks
    gemm_out<<<dim3(LLM_/64,1), 256, 0, stream>>>(fe, H_, wb_in, H_,
                                                  H_, B_*KTOK, out, LLM_, projb, 0);
}